// Round 9
// baseline (380.256 us; speedup 1.0000x reference)
//
#include <hip/hip_runtime.h>
#include <cstddef>

constexpr int N_ = 65536;
constexpr int K_ = 16;
constexpr int E_ = N_ * K_;      // 1048576
constexpr int C_ = 64;
#define EPS_ 1e-5f
#define SW 68   // LDS row stride (words) for GEMM tiles

typedef unsigned int uint_t;
typedef float v2f __attribute__((ext_vector_type(2)));

// bf16 helpers (RNE pack, cheap unpack)
__device__ __forceinline__ uint_t bf16_rne(float f) {
    uint_t u = __float_as_uint(f);
    return (u + 0x7fffu + ((u >> 16) & 1u)) >> 16;
}
__device__ __forceinline__ float bf16_lo(uint_t p) { return __uint_as_float(p << 16); }
__device__ __forceinline__ float bf16_hi(uint_t p) { return __uint_as_float(p & 0xffff0000u); }
__device__ __forceinline__ v2f v2max0(v2f a) {
    v2f r; r.x = fmaxf(a.x, 0.f); r.y = fmaxf(a.y, 0.f); return r;
}

// ---------------------------------------------------------------------------
// BN stats reducer (R2: parallel, 4x unrolled, LDS tree).
__global__ __launch_bounds__(1024)
void k_reduce_bn(const float* __restrict__ part, int P, int nchp, int nch,
                 float invM, const float* __restrict__ g,
                 const float* __restrict__ b, float* __restrict__ ss)
{
    int t = threadIdx.x;
    int c = t & (nchp - 1);
    int r = t / nchp;
    int R = 1024 / nchp;
    int stride = 2 * nchp;
    float s0 = 0.f, s1 = 0.f, s2 = 0.f, s3 = 0.f;
    float q0 = 0.f, q1 = 0.f, q2 = 0.f, q3 = 0.f;
    int p = r;
    for (; p + 3 * R < P; p += 4 * R) {
        int i0 = p * stride + c;
        int i1 = (p + R) * stride + c;
        int i2 = (p + 2 * R) * stride + c;
        int i3 = (p + 3 * R) * stride + c;
        s0 += part[i0];        s1 += part[i1];
        s2 += part[i2];        s3 += part[i3];
        q0 += part[i0 + nchp]; q1 += part[i1 + nchp];
        q2 += part[i2 + nchp]; q3 += part[i3 + nchp];
    }
    for (; p < P; p += R) {
        s0 += part[p * stride + c];
        q0 += part[p * stride + nchp + c];
    }
    float s = (s0 + s1) + (s2 + s3);
    float q = (q0 + q1) + (q2 + q3);
    __shared__ float reds[1024], redq[1024];
    reds[t] = s; redq[t] = q;
    __syncthreads();
    for (int off = 512; off >= nchp; off >>= 1) {
        if (t < off) { reds[t] += reds[t + off]; redq[t] += redq[t + off]; }
        __syncthreads();
    }
    if (t < nch) {
        float mean = reds[t] * invM;
        float var  = fmaxf(redq[t] * invM - mean * mean, 0.f);
        float sc = g[t] * rsqrtf(var + EPS_);
        ss[t] = sc;
        ss[nchp + t] = b[t] - mean * sc;
    }
}

// ---------------------------------------------------------------------------
// R5 GEMM structure (LDS-tiled, coalesced).
__device__ __forceinline__ void stage_x(const float* __restrict__ in,
                                        const float* __restrict__ ss,
                                        float* __restrict__ Xs, int row0, int t)
{
#pragma unroll
    for (int it = 0; it < 4; ++it) {
        int m = t + 256 * it;
        int r = m >> 4, j = m & 15;
        float4 v = ((const float4*)in)[(size_t)(row0 + r) * 16 + j];
        if (ss) {
            float4 sc = ((const float4*)ss)[j];
            float4 sh = ((const float4*)(ss + 64))[j];
            v.x = fmaxf(fmaf(v.x, sc.x, sh.x), 0.f);
            v.y = fmaxf(fmaf(v.y, sc.y, sh.y), 0.f);
            v.z = fmaxf(fmaf(v.z, sc.z, sh.z), 0.f);
            v.w = fmaxf(fmaf(v.w, sc.w, sh.w), 0.f);
        }
        *(float4*)&Xs[r * SW + 4 * j] = v;
    }
}

__device__ __forceinline__ void stage_w(const float* __restrict__ W,
                                        float* __restrict__ Ws, int t)
{
#pragma unroll
    for (int it = 0; it < 4; ++it) {
        int m = t + 256 * it;
        int r = m >> 4, j = m & 15;
        *(float4*)&Ws[r * SW + 4 * j] = ((const float4*)W)[m];
    }
}

__device__ __forceinline__ void compute_tile(const float* __restrict__ Xs,
                                             const float* __restrict__ Ws,
                                             int tx, int ty, float acc[4][4])
{
#pragma unroll
    for (int r = 0; r < 4; ++r)
#pragma unroll
        for (int c = 0; c < 4; ++c) acc[r][c] = 0.f;
    for (int kc = 0; kc < 16; ++kc) {
        float4 xf[4], wf[4];
#pragma unroll
        for (int r = 0; r < 4; ++r)
            xf[r] = *(const float4*)&Xs[(tx + 16 * r) * SW + 4 * kc];
#pragma unroll
        for (int c = 0; c < 4; ++c)
            wf[c] = *(const float4*)&Ws[(ty + 16 * c) * SW + 4 * kc];
#pragma unroll
        for (int r = 0; r < 4; ++r)
#pragma unroll
            for (int c = 0; c < 4; ++c) {
                acc[r][c] = fmaf(xf[r].x, wf[c].x, acc[r][c]);
                acc[r][c] = fmaf(xf[r].y, wf[c].y, acc[r][c]);
                acc[r][c] = fmaf(xf[r].z, wf[c].z, acc[r][c]);
                acc[r][c] = fmaf(xf[r].w, wf[c].w, acc[r][c]);
            }
    }
}

__device__ __forceinline__ void write_tile(float* __restrict__ buf, int tx, int ty,
                                           const float acc[4][4],
                                           const float* __restrict__ bias,
                                           float* __restrict__ out, int row0, int t)
{
    __syncthreads();
#pragma unroll
    for (int r = 0; r < 4; ++r)
#pragma unroll
        for (int c = 0; c < 4; ++c)
            buf[(tx + 16 * r) * SW + ty + 16 * c] = acc[r][c];
    __syncthreads();
#pragma unroll
    for (int it = 0; it < 4; ++it) {
        int m = t + 256 * it;
        int r = m >> 4, j = m & 15;
        float4 v = *(const float4*)&buf[r * SW + 4 * j];
        if (bias) {
            float4 bv = ((const float4*)bias)[j];
            v.x += bv.x; v.y += bv.y; v.z += bv.z; v.w += bv.w;
        }
        ((float4*)out)[(size_t)(row0 + r) * 16 + j] = v;
    }
    __syncthreads();
}

// bf16 variant: rounds to bf16 (RNE) and stores 8B/lane coalesced.
__device__ __forceinline__ void write_tile_bf16(float* __restrict__ buf, int tx, int ty,
                                                const float acc[4][4],
                                                const float* __restrict__ bias,
                                                unsigned short* __restrict__ out,
                                                int row0, int t)
{
    __syncthreads();
#pragma unroll
    for (int r = 0; r < 4; ++r)
#pragma unroll
        for (int c = 0; c < 4; ++c)
            buf[(tx + 16 * r) * SW + ty + 16 * c] = acc[r][c];
    __syncthreads();
#pragma unroll
    for (int it = 0; it < 4; ++it) {
        int m = t + 256 * it;
        int r = m >> 4, j = m & 15;
        float4 v = *(const float4*)&buf[r * SW + 4 * j];
        if (bias) {
            float4 bv = ((const float4*)bias)[j];
            v.x += bv.x; v.y += bv.y; v.z += bv.z; v.w += bv.w;
        }
        uint2 o;
        o.x = bf16_rne(v.x) | (bf16_rne(v.y) << 16);
        o.y = bf16_rne(v.z) | (bf16_rne(v.w) << 16);
        ((uint2*)out)[(size_t)(row0 + r) * 16 + j] = o;
    }
    __syncthreads();
}

// y = (optional relu(bn(in))) @ W^T. R9: fused column-stats epilogue — the
// store loop's j=t&15 is thread-invariant, so each thread accumulates its 4
// channels over its 4 rows; Xs (dead after compute) is the reduce scratch.
__global__ __launch_bounds__(256)
void k_gemm_tile(const float* __restrict__ in, const float* __restrict__ W,
                 const float* __restrict__ bias, const float* __restrict__ ss,
                 float* __restrict__ out, float* __restrict__ part)
{
    __shared__ float Xs[64 * SW];
    __shared__ float Ws[64 * SW];
    int t = threadIdx.x, tx = t & 15, ty = t >> 4;
    int row0 = blockIdx.x * 64;
    stage_x(in, ss, Xs, row0, t);
    stage_w(W, Ws, t);
    __syncthreads();
    float acc[4][4];
    compute_tile(Xs, Ws, tx, ty, acc);
    // epilogue: transpose through Ws (W dead), store coalesced, collect stats
    __syncthreads();
#pragma unroll
    for (int r = 0; r < 4; ++r)
#pragma unroll
        for (int c = 0; c < 4; ++c)
            Ws[(tx + 16 * r) * SW + ty + 16 * c] = acc[r][c];
    __syncthreads();
    float s0 = 0, s1 = 0, s2 = 0, s3 = 0, q0 = 0, q1 = 0, q2 = 0, q3 = 0;
#pragma unroll
    for (int it = 0; it < 4; ++it) {
        int m = t + 256 * it;
        int r = m >> 4, j = m & 15;
        float4 v = *(const float4*)&Ws[r * SW + 4 * j];
        if (bias) {
            float4 bv = ((const float4*)bias)[j];
            v.x += bv.x; v.y += bv.y; v.z += bv.z; v.w += bv.w;
        }
        ((float4*)out)[(size_t)(row0 + r) * 16 + j] = v;
        s0 += v.x; q0 = fmaf(v.x, v.x, q0);
        s1 += v.y; q1 = fmaf(v.y, v.y, q1);
        s2 += v.z; q2 = fmaf(v.z, v.z, q2);
        s3 += v.w; q3 = fmaf(v.w, v.w, q3);
    }
    float4* scr = (float4*)Xs;   // Xs dead after compute
    scr[t]       = make_float4(s0, s1, s2, s3);
    scr[256 + t] = make_float4(q0, q1, q2, q3);
    __syncthreads();
    if (t < 16) {   // thread t handles j=t (channels 4t..4t+3)
        float4 S = make_float4(0, 0, 0, 0), Q = make_float4(0, 0, 0, 0);
#pragma unroll
        for (int k = 0; k < 16; ++k) {
            float4 a = scr[k * 16 + t], b = scr[256 + k * 16 + t];
            S.x += a.x; S.y += a.y; S.z += a.z; S.w += a.w;
            Q.x += b.x; Q.y += b.y; Q.z += b.z; Q.w += b.w;
        }
        *(float4*)&part[blockIdx.x * 128 + 4 * t]      = S;
        *(float4*)&part[blockIdx.x * 128 + 64 + 4 * t] = Q;
    }
}

// h = relu(bn1(y)); asrc16 = bf16(h@Wa^T+ba); adst = h@Wb^T+bb (f32);
// hw16 = bf16(h@Wc^T+bc)
__global__ __launch_bounds__(256)
void k_gemm3_tile(const float* __restrict__ y, const float* __restrict__ ss,
                  const float* __restrict__ Wa, const float* __restrict__ ba,
                  const float* __restrict__ Wb, const float* __restrict__ bb,
                  const float* __restrict__ Wc, const float* __restrict__ bc,
                  unsigned short* __restrict__ oa16, float* __restrict__ ob,
                  unsigned short* __restrict__ oc16)
{
    __shared__ float Xs[64 * SW];
    __shared__ float Ws[64 * SW];
    int t = threadIdx.x, tx = t & 15, ty = t >> 4;
    int row0 = blockIdx.x * 64;
    stage_x(y, ss, Xs, row0, t);
    stage_w(Wa, Ws, t);
    __syncthreads();
    float acc[4][4];
    compute_tile(Xs, Ws, tx, ty, acc);
    write_tile_bf16(Ws, tx, ty, acc, ba, oa16, row0, t);
    stage_w(Wb, Ws, t);
    __syncthreads();
    compute_tile(Xs, Ws, tx, ty, acc);
    write_tile(Ws, tx, ty, acc, bb, ob, row0, t);
    stage_w(Wc, Ws, t);
    __syncthreads();
    compute_tile(Xs, Ws, tx, ty, acc);
    write_tile_bf16(Ws, tx, ty, acc, bc, oc16, row0, t);
}

// ---------------------------------------------------------------------------
// Stats of u = rel @ pos_w1^T + pos_b1 over E edges (3 channels, pad 4).
__global__ __launch_bounds__(256)
void k_pos_stats(const float* __restrict__ pos, const int* __restrict__ src,
                 const float* __restrict__ pw1, const float* __restrict__ pb1,
                 float* __restrict__ part)
{
    float s0 = 0, s1 = 0, s2 = 0, q0 = 0, q1 = 0, q2 = 0;
    int tid = blockIdx.x * 256 + threadIdx.x;
    for (int e = tid; e < E_; e += 1024 * 256) {
        int si = src[e], di = e >> 4;
        float rx = pos[3 * si + 0] - pos[3 * di + 0];
        float ry = pos[3 * si + 1] - pos[3 * di + 1];
        float rz = pos[3 * si + 2] - pos[3 * di + 2];
        float u0 = fmaf(rx, pw1[0], fmaf(ry, pw1[1], fmaf(rz, pw1[2], pb1[0])));
        float u1 = fmaf(rx, pw1[3], fmaf(ry, pw1[4], fmaf(rz, pw1[5], pb1[1])));
        float u2 = fmaf(rx, pw1[6], fmaf(ry, pw1[7], fmaf(rz, pw1[8], pb1[2])));
        s0 += u0; q0 = fmaf(u0, u0, q0);
        s1 += u1; q1 = fmaf(u1, u1, q1);
        s2 += u2; q2 = fmaf(u2, u2, q2);
    }
#pragma unroll
    for (int m = 1; m < 64; m <<= 1) {
        s0 += __shfl_xor(s0, m, 64); s1 += __shfl_xor(s1, m, 64); s2 += __shfl_xor(s2, m, 64);
        q0 += __shfl_xor(q0, m, 64); q1 += __shfl_xor(q1, m, 64); q2 += __shfl_xor(q2, m, 64);
    }
    __shared__ float red[4][8];
    int wv = threadIdx.x >> 6, ln = threadIdx.x & 63;
    if (ln == 0) {
        red[wv][0] = s0; red[wv][1] = s1; red[wv][2] = s2; red[wv][3] = 0.f;
        red[wv][4] = q0; red[wv][5] = q1; red[wv][6] = q2; red[wv][7] = 0.f;
    }
    __syncthreads();
    if (threadIdx.x < 8)
        part[blockIdx.x * 8 + threadIdx.x] =
            red[0][threadIdx.x] + red[1][threadIdx.x] + red[2][threadIdx.x] + red[3][threadIdx.x];
}

// ---------------------------------------------------------------------------
// R9 edge kernels: group-per-node + per-lane d-precompute + bf16 tables +
// packed-f32 (v2f) channel-pair math (v_pk_fma_f32 on gfx950).
// Packed del coefficients per lane (channels c0..c0+3 as pairs 01 / 23):
//  del01 = {pb.x,pb.y} + d0*{p0.x,p0.w} + d1*{p0.y,p1.x} + d2*{p0.z,p1.y}
//  del23 = {pb.z,pb.w} + d0*{p1.z,p2.y} + d1*{p1.w,p2.z} + d2*{p2.x,p2.w}

struct DelW {
    v2f A0, A1, A2, B0;   // pair 01
    v2f C0, C1, C2, D0;   // pair 23
};
__device__ __forceinline__ DelW load_delw(const float* __restrict__ pw2,
                                          const float* __restrict__ pb2, int l)
{
    float4 p0 = *(const float4*)(pw2 + 12 * l);
    float4 p1 = *(const float4*)(pw2 + 12 * l + 4);
    float4 p2 = *(const float4*)(pw2 + 12 * l + 8);
    float4 pb = *(const float4*)(pb2 + 4 * l);
    DelW w;
    w.A0 = (v2f){p0.x, p0.w}; w.A1 = (v2f){p0.y, p1.x}; w.A2 = (v2f){p0.z, p1.y};
    w.B0 = (v2f){pb.x, pb.y};
    w.C0 = (v2f){p1.z, p2.y}; w.C1 = (v2f){p1.w, p2.z}; w.C2 = (v2f){p2.x, p2.w};
    w.D0 = (v2f){pb.z, pb.w};
    return w;
}

// Stats of a = bf16(a_src)[src]-a_dst[dst]+delta. Grid 2048 x 256.
__global__ __launch_bounds__(256)
void k_abn1_stats(const float* __restrict__ pos, const int* __restrict__ src,
                  const unsigned short* __restrict__ asrc16,
                  const float* __restrict__ adst,
                  const float* __restrict__ pw1, const float* __restrict__ pb1,
                  const float* __restrict__ sspos, const float* __restrict__ pw2,
                  const float* __restrict__ pb2, float* __restrict__ part)
{
    int t = threadIdx.x;
    int l = t & 15, g = t >> 4, wv = t >> 6;
    int c0 = 4 * l;
    DelW W = load_delw(pw2, pb2, l);
    v2f sa01 = {0.f, 0.f}, sa23 = {0.f, 0.f};
    v2f qa01 = {0.f, 0.f}, qa23 = {0.f, 0.f};
#pragma unroll
    for (int nn = 0; nn < 2; ++nn) {
        int n = blockIdx.x * 32 + nn * 16 + g;
        float4 dvf = *(const float4*)(adst + (size_t)n * 64 + c0);
        v2f dv01 = {dvf.x, dvf.y}, dv23 = {dvf.z, dvf.w};
        float pnx = pos[3 * n + 0], pny = pos[3 * n + 1], pnz = pos[3 * n + 2];
        int si_l = src[n * 16 + l];
        float rx = pos[3 * si_l + 0] - pnx;
        float ry = pos[3 * si_l + 1] - pny;
        float rz = pos[3 * si_l + 2] - pnz;
        float u0 = fmaf(rx, pw1[0], fmaf(ry, pw1[1], fmaf(rz, pw1[2], pb1[0])));
        float u1 = fmaf(rx, pw1[3], fmaf(ry, pw1[4], fmaf(rz, pw1[5], pb1[1])));
        float u2 = fmaf(rx, pw1[6], fmaf(ry, pw1[7], fmaf(rz, pw1[8], pb1[2])));
        float dl0 = fmaxf(fmaf(u0, sspos[0], sspos[4]), 0.f);
        float dl1 = fmaxf(fmaf(u1, sspos[1], sspos[5]), 0.f);
        float dl2 = fmaxf(fmaf(u2, sspos[2], sspos[6]), 0.f);
        for (int k = 0; k < 16; ++k) {
            int si = __shfl(si_l, k, 16);
            float d0 = __shfl(dl0, k, 16);
            float d1 = __shfl(dl1, k, 16);
            float d2 = __shfl(dl2, k, 16);
            uint2 raw = ((const uint2*)asrc16)[(size_t)si * 16 + l];
            v2f av01 = {bf16_lo(raw.x), bf16_hi(raw.x)};
            v2f av23 = {bf16_lo(raw.y), bf16_hi(raw.y)};
            v2f del01 = W.B0 + d0 * W.A0; del01 = del01 + d1 * W.A1; del01 = del01 + d2 * W.A2;
            v2f del23 = W.D0 + d0 * W.C0; del23 = del23 + d1 * W.C1; del23 = del23 + d2 * W.C2;
            v2f a01 = (av01 - dv01) + del01;
            v2f a23 = (av23 - dv23) + del23;
            sa01 = sa01 + a01; qa01 = qa01 + a01 * a01;
            sa23 = sa23 + a23; qa23 = qa23 + a23 * a23;
        }
    }
    float sa0 = sa01.x, sa1 = sa01.y, sa2 = sa23.x, sa3 = sa23.y;
    float qa0 = qa01.x, qa1 = qa01.y, qa2 = qa23.x, qa3 = qa23.y;
#pragma unroll
    for (int m = 16; m <= 32; m <<= 1) {
        sa0 += __shfl_xor(sa0, m, 64); sa1 += __shfl_xor(sa1, m, 64);
        sa2 += __shfl_xor(sa2, m, 64); sa3 += __shfl_xor(sa3, m, 64);
        qa0 += __shfl_xor(qa0, m, 64); qa1 += __shfl_xor(qa1, m, 64);
        qa2 += __shfl_xor(qa2, m, 64); qa3 += __shfl_xor(qa3, m, 64);
    }
    __shared__ float red[4][128];
    if ((t & 63) < 16) {
        red[wv][c0 + 0] = sa0; red[wv][c0 + 1] = sa1;
        red[wv][c0 + 2] = sa2; red[wv][c0 + 3] = sa3;
        red[wv][64 + c0 + 0] = qa0; red[wv][64 + c0 + 1] = qa1;
        red[wv][64 + c0 + 2] = qa2; red[wv][64 + c0 + 3] = qa3;
    }
    __syncthreads();
    if (t < 128)
        part[blockIdx.x * 128 + t] = red[0][t] + red[1][t] + red[2][t] + red[3][t];
}

// ---------------------------------------------------------------------------
// t1 = relu(abn1(a)) @ attn_w1^T + attn_b1; abn2 stats. Grid 2048 x 256.
__global__ __launch_bounds__(256)
void k_edge_t1(const float* __restrict__ pos, const int* __restrict__ src,
               const unsigned short* __restrict__ asrc16,
               const float* __restrict__ adst,
               const float* __restrict__ pw1, const float* __restrict__ pb1,
               const float* __restrict__ sspos, const float* __restrict__ pw2,
               const float* __restrict__ pb2, const float* __restrict__ ssa1,
               const float* __restrict__ aw1, const float* __restrict__ ab1,
               float* __restrict__ t1, float* __restrict__ part)
{
    int t = threadIdx.x;
    int l = t & 15, g = t >> 4, wv = t >> 6;
    int c0 = 4 * l;
    int ch = 4 * (l & 1) + 2 * ((l >> 1) & 1) + ((l >> 2) & 1);
    float abv = ab1[ch];
    DelW W = load_delw(pw2, pb2, l);
    float4 scf = *(const float4*)(ssa1 + c0);
    float4 shf = *(const float4*)(ssa1 + 64 + c0);
    v2f sc01 = {scf.x, scf.y}, sc23 = {scf.z, scf.w};
    v2f sh01 = {shf.x, shf.y}, sh23 = {shf.z, shf.w};
    // packed attn_w1: wp[p][c] = {aw1[2p][c0+c], aw1[2p+1][c0+c]}
    v2f wp[4][4];
#pragma unroll
    for (int p = 0; p < 4; ++p)
#pragma unroll
        for (int c = 0; c < 4; ++c)
            wp[p][c] = (v2f){aw1[(2 * p) * 64 + c0 + c], aw1[(2 * p + 1) * 64 + c0 + c]};
    float sse = 0.f, ssq = 0.f;
#pragma unroll
    for (int nn = 0; nn < 2; ++nn) {
        int n = blockIdx.x * 32 + nn * 16 + g;
        float4 dvf = *(const float4*)(adst + (size_t)n * 64 + c0);
        v2f dv01 = {dvf.x, dvf.y}, dv23 = {dvf.z, dvf.w};
        float pnx = pos[3 * n + 0], pny = pos[3 * n + 1], pnz = pos[3 * n + 2];
        int si_l = src[n * 16 + l];
        float rx = pos[3 * si_l + 0] - pnx;
        float ry = pos[3 * si_l + 1] - pny;
        float rz = pos[3 * si_l + 2] - pnz;
        float u0 = fmaf(rx, pw1[0], fmaf(ry, pw1[1], fmaf(rz, pw1[2], pb1[0])));
        float u1 = fmaf(rx, pw1[3], fmaf(ry, pw1[4], fmaf(rz, pw1[5], pb1[1])));
        float u2 = fmaf(rx, pw1[6], fmaf(ry, pw1[7], fmaf(rz, pw1[8], pb1[2])));
        float dl0 = fmaxf(fmaf(u0, sspos[0], sspos[4]), 0.f);
        float dl1 = fmaxf(fmaf(u1, sspos[1], sspos[5]), 0.f);
        float dl2 = fmaxf(fmaf(u2, sspos[2], sspos[6]), 0.f);
        for (int k = 0; k < 16; ++k) {
            int si = __shfl(si_l, k, 16);
            float d0 = __shfl(dl0, k, 16);
            float d1 = __shfl(dl1, k, 16);
            float d2 = __shfl(dl2, k, 16);
            uint2 raw = ((const uint2*)asrc16)[(size_t)si * 16 + l];
            v2f av01 = {bf16_lo(raw.x), bf16_hi(raw.x)};
            v2f av23 = {bf16_lo(raw.y), bf16_hi(raw.y)};
            v2f del01 = W.B0 + d0 * W.A0; del01 = del01 + d1 * W.A1; del01 = del01 + d2 * W.A2;
            v2f del23 = W.D0 + d0 * W.C0; del23 = del23 + d1 * W.C1; del23 = del23 + d2 * W.C2;
            v2f a01 = (av01 - dv01) + del01;
            v2f a23 = (av23 - dv23) + del23;
            v2f an01 = v2max0(a01 * sc01 + sh01);
            v2f an23 = v2max0(a23 * sc23 + sh23);
            v2f tpa[4];
#pragma unroll
            for (int p = 0; p < 4; ++p) {
                v2f acc = an01.x * wp[p][0];
                acc = acc + an01.y * wp[p][1];
                acc = acc + an23.x * wp[p][2];
                acc = acc + an23.y * wp[p][3];
                tpa[p] = acc;
            }
            float tp[8] = {tpa[0].x, tpa[0].y, tpa[1].x, tpa[1].y,
                           tpa[2].x, tpa[2].y, tpa[3].x, tpa[3].y};
            // reduce-scatter: 8 -> 4 -> 2 -> 1 values
            float s4[4];
#pragma unroll
            for (int j = 0; j < 4; ++j) {
                float send = (l & 1) ? tp[j] : tp[j + 4];
                float recv = __shfl_xor(send, 1, 64);
                s4[j] = ((l & 1) ? tp[j + 4] : tp[j]) + recv;
            }
            float s2[2];
#pragma unroll
            for (int j = 0; j < 2; ++j) {
                float send = (l & 2) ? s4[j] : s4[j + 2];
                float recv = __shfl_xor(send, 2, 64);
                s2[j] = ((l & 2) ? s4[j + 2] : s4[j]) + recv;
            }
            float send = (l & 4) ? s2[0] : s2[1];
            float recv = __shfl_xor(send, 4, 64);
            float s1 = ((l & 4) ? s2[1] : s2[0]) + recv;
            s1 += __shfl_xor(s1, 8, 64);
            float o = s1 + abv;
            if (l < 8) t1[(size_t)(n * 16 + k) * 8 + ch] = o;
            sse += o; ssq = fmaf(o, o, ssq);
        }
    }
#pragma unroll
    for (int m = 16; m <= 32; m <<= 1) {
        sse += __shfl_xor(sse, m, 64);
        ssq += __shfl_xor(ssq, m, 64);
    }
    __shared__ float red[4][16];
    if ((t & 63) < 8) { red[wv][ch] = sse; red[wv][8 + ch] = ssq; }
    __syncthreads();
    if (t < 16)
        part[blockIdx.x * 16 + t] = red[0][t] + red[1][t] + red[2][t] + red[3][t];
}

// ---------------------------------------------------------------------------
// Softmax + weighted aggregate, group-per-node; fused bn2-stats epilogue.
// Grid 4096 x 256 (16 nodes/blk).
__global__ __launch_bounds__(256)
void k_node_aggr(const float* __restrict__ pos, const int* __restrict__ src,
                 const float* __restrict__ t1, const float* __restrict__ ssa2,
                 const float* __restrict__ aw2, const float* __restrict__ ab2,
                 const unsigned short* __restrict__ hw16,
                 const float* __restrict__ sspos,
                 const float* __restrict__ pw1, const float* __restrict__ pb1,
                 const float* __restrict__ pw2, const float* __restrict__ pb2,
                 float* __restrict__ out, float* __restrict__ part)
{
    __shared__ float alds[16][196];   // [group][k*12 + ch8]; later stats scratch
    int t = threadIdx.x, l = t & 15, g = t >> 4;
    int c0 = 4 * l;
    DelW W = load_delw(pw2, pb2, l);
    int alof = (l & 1) * 4;
    int n = blockIdx.x * 16 + g;
    int e = n * 16 + l;
    // ---- phase A: per-edge attention logits + softmax over the group
    const float4* t4 = (const float4*)(t1 + (size_t)e * 8);
    float4 ta = t4[0], tb = t4[1];
    float tv[8] = {ta.x, ta.y, ta.z, ta.w, tb.x, tb.y, tb.z, tb.w};
    float tn[8];
#pragma unroll
    for (int j = 0; j < 8; ++j)
        tn[j] = fmaxf(fmaf(tv[j], ssa2[j], ssa2[8 + j]), 0.f);
    float al[8];
#pragma unroll
    for (int j = 0; j < 8; ++j) {
        float acc = ab2[j];
#pragma unroll
        for (int i = 0; i < 8; ++i) acc = fmaf(tn[i], aw2[j * 8 + i], acc);
        float m = acc;
#pragma unroll
        for (int msk = 1; msk < 16; msk <<= 1) m = fmaxf(m, __shfl_xor(m, msk, 64));
        float ex = __expf(acc - m);
        float sm = ex;
#pragma unroll
        for (int msk = 1; msk < 16; msk <<= 1) sm += __shfl_xor(sm, msk, 64);
        al[j] = ex / sm;
    }
    *(float4*)&alds[g][l * 12]     = make_float4(al[0], al[1], al[2], al[3]);
    *(float4*)&alds[g][l * 12 + 4] = make_float4(al[4], al[5], al[6], al[7]);
    int silane = src[e];
    float pnx = pos[3 * n + 0], pny = pos[3 * n + 1], pnz = pos[3 * n + 2];
    // own-edge d
    float rx = pos[3 * silane + 0] - pnx;
    float ry = pos[3 * silane + 1] - pny;
    float rz = pos[3 * silane + 2] - pnz;
    float u0 = fmaf(rx, pw1[0], fmaf(ry, pw1[1], fmaf(rz, pw1[2], pb1[0])));
    float u1 = fmaf(rx, pw1[3], fmaf(ry, pw1[4], fmaf(rz, pw1[5], pb1[1])));
    float u2 = fmaf(rx, pw1[6], fmaf(ry, pw1[7], fmaf(rz, pw1[8], pb1[2])));
    float dl0 = fmaxf(fmaf(u0, sspos[0], sspos[4]), 0.f);
    float dl1 = fmaxf(fmaf(u1, sspos[1], sspos[5]), 0.f);
    float dl2 = fmaxf(fmaf(u2, sspos[2], sspos[6]), 0.f);
    // ---- phase B: accumulate own 4 channels over the node's 16 edges
    v2f acc01 = {0.f, 0.f}, acc23 = {0.f, 0.f};
#pragma unroll 4
    for (int k = 0; k < 16; ++k) {
        int sk = __shfl(silane, k, 16);
        float d0 = __shfl(dl0, k, 16);
        float d1 = __shfl(dl1, k, 16);
        float d2 = __shfl(dl2, k, 16);
        uint2 raw = ((const uint2*)hw16)[(size_t)sk * 16 + l];
        v2f hv01 = {bf16_lo(raw.x), bf16_hi(raw.x)};
        v2f hv23 = {bf16_lo(raw.y), bf16_hi(raw.y)};
        float4 alv = *(const float4*)&alds[g][k * 12 + alof];
        v2f al01 = {alv.x, alv.y}, al23 = {alv.z, alv.w};
        v2f del01 = W.B0 + d0 * W.A0; del01 = del01 + d1 * W.A1; del01 = del01 + d2 * W.A2;
        v2f del23 = W.D0 + d0 * W.C0; del23 = del23 + d1 * W.C1; del23 = del23 + d2 * W.C2;
        acc01 = acc01 + al01 * (hv01 + del01);
        acc23 = acc23 + al23 * (hv23 + del23);
    }
    float a0 = acc01.x, a1 = acc01.y, a2 = acc23.x, a3 = acc23.y;
    *(float4*)(out + (size_t)n * 64 + c0) = make_float4(a0, a1, a2, a3);
    // ---- fused bn2 stats: reduce over the block's 16 nodes per channel
    __syncthreads();   // all alds reads done
    float4* scr = (float4*)&alds[0][0];   // 512 float4 needed <= 3136 floats OK
    scr[g * 16 + l]       = make_float4(a0, a1, a2, a3);
    scr[256 + g * 16 + l] = make_float4(a0 * a0, a1 * a1, a2 * a2, a3 * a3);
    __syncthreads();
    if (t < 16) {   // thread t handles l=t (channels 4t..4t+3)
        float4 S = make_float4(0, 0, 0, 0), Q = make_float4(0, 0, 0, 0);
#pragma unroll
        for (int k = 0; k < 16; ++k) {
            float4 a = scr[k * 16 + t], b = scr[256 + k * 16 + t];
            S.x += a.x; S.y += a.y; S.z += a.z; S.w += a.w;
            Q.x += b.x; Q.y += b.y; Q.z += b.z; Q.w += b.w;
        }
        *(float4*)&part[blockIdx.x * 128 + 4 * t]      = S;
        *(float4*)&part[blockIdx.x * 128 + 64 + 4 * t] = Q;
    }
}

// ---------------------------------------------------------------------------
// out = relu(bn3(y3) + x_skip)
__global__ __launch_bounds__(256)
void k_final(const float* __restrict__ y3, const float* __restrict__ ss3,
             const float* __restrict__ x, float* __restrict__ out)
{
    int i = blockIdx.x * 256 + threadIdx.x;   // float4 index
    int c4 = i & 15;
    float4 sc = ((const float4*)ss3)[c4];
    float4 sh = ((const float4*)(ss3 + 64))[c4];
    float4 v  = ((const float4*)y3)[i];
    float4 xs = ((const float4*)x)[i];
    float4 o;
    o.x = fmaxf(fmaf(v.x, sc.x, sh.x) + xs.x, 0.f);
    o.y = fmaxf(fmaf(v.y, sc.y, sh.y) + xs.y, 0.f);
    o.z = fmaxf(fmaf(v.z, sc.z, sh.z) + xs.z, 0.f);
    o.w = fmaxf(fmaf(v.w, sc.w, sh.w) + xs.w, 0.f);
    ((float4*)out)[i] = o;
}

// ---------------------------------------------------------------------------
extern "C" void kernel_launch(void* const* d_in, const int* in_sizes, int n_in,
                              void* d_out, int out_size, void* d_ws, size_t ws_size,
                              hipStream_t stream)
{
    const float* x    = (const float*)d_in[0];
    const float* pos  = (const float*)d_in[1];
    const int*   src  = (const int*)d_in[2];           // edge_index row 0
    const float* W_in = (const float*)d_in[3];
    const float* W_out= (const float*)d_in[4];
    const float* pw1  = (const float*)d_in[5];
    const float* pb1  = (const float*)d_in[6];
    const float* pbg  = (const float*)d_in[7];
    const float* pbb  = (const float*)d_in[8];
    const float* pw2  = (const float*)d_in[9];
    const float* pb2  = (const float*)d_in[10];
    const float* a1g  = (const float*)d_in[11];
    const float* a1b  = (const float*)d_in[12];
    const float* aw1  = (const float*)d_in[13];
    const float* ab1  = (const float*)d_in[14];
    const float* a2g  = (const float*)d_in[15];
    const float* a2b  = (const float*)d_in[16];
    const float* aw2  = (const float*)d_in[17];
    const float* ab2  = (const float*)d_in[18];
    const float* linw = (const float*)d_in[19];
    const float* linb = (const float*)d_in[20];
    const float* srcw = (const float*)d_in[21];
    const float* srcb = (const float*)d_in[22];
    const float* dstw = (const float*)d_in[23];
    const float* dstb = (const float*)d_in[24];
    const float* bn1g = (const float*)d_in[25];
    const float* bn1b = (const float*)d_in[26];
    const float* bn2g = (const float*)d_in[27];
    const float* bn2b = (const float*)d_in[28];
    const float* bn3g = (const float*)d_in[29];
    const float* bn3b = (const float*)d_in[30];
    float* outp = (float*)d_out;

    float* ws = (float*)d_ws;
    const size_t NC = (size_t)N_ * C_;
    float* buf_y     = ws;                       // y1, later y3
    float* buf_adst  = ws + NC;                  // a_dst f32; later reused as out
    unsigned short* asrc16 = (unsigned short*)(ws + 2 * NC);       // NC/2 floats
    unsigned short* hw16   = (unsigned short*)(ws + 2 * NC + NC / 2);
    float* buf_t1    = ws + 3 * NC;              // [E,8] f32
    float* pbase     = ws + 3 * NC + (size_t)E_ * 8;
    float* p_bn1  = pbase;                 // 1024*128
    float* p_pos  = p_bn1  + 1024 * 128;   // 1024*8
    float* p_abn2 = p_pos  + 1024 * 8;     // 2048*16
    float* p_bn2  = p_abn2 + 2048 * 16;    // 4096*128
    float* p_bn3  = p_bn2  + 4096 * 128;   // 1024*128
    float* ssb    = p_bn3  + 1024 * 128;
    float* ss_bn1 = ssb;         // [scale 64][shift 64]
    float* ss_pos = ssb + 128;   // [scale 4][shift 4]
    float* ss_a1  = ssb + 136;   // 128
    float* ss_a2  = ssb + 264;   // 16
    float* ss_bn2 = ssb + 280;   // 128
    float* ss_bn3 = ssb + 408;   // 128
    // p_abn1 (2048*128 = 1 MB) aliases buf_t1: consumed by its reducer BEFORE
    // k_edge_t1 writes t1 into the same region.
    float* p_abn1 = buf_t1;
    // buf_out aliases buf_adst: adst last read by k_edge_t1 (step 9).
    float* buf_out = buf_adst;

    // 1) y1 = x @ W_in^T (+ fused bn1 partials)
    k_gemm_tile<<<1024, 256, 0, stream>>>(x, W_in, nullptr, nullptr, buf_y, p_bn1);
    k_reduce_bn<<<1, 1024, 0, stream>>>(p_bn1, 1024, 64, 64, 1.f / N_, bn1g, bn1b, ss_bn1);
    // 2) h = relu(bn1(y1)); asrc16 (bf16) / adst (f32) / hw16 (bf16)
    k_gemm3_tile<<<1024, 256, 0, stream>>>(buf_y, ss_bn1, srcw, srcb, dstw, dstb, linw, linb,
                                           asrc16, buf_adst, hw16);
    // 3) pos-BN stats
    k_pos_stats<<<1024, 256, 0, stream>>>(pos, src, pw1, pb1, p_pos);
    k_reduce_bn<<<1, 1024, 0, stream>>>(p_pos, 1024, 4, 3, 1.f / E_, pbg, pbb, ss_pos);
    // 4) attn_bn1 stats
    k_abn1_stats<<<2048, 256, 0, stream>>>(pos, src, asrc16, buf_adst,
                                           pw1, pb1, ss_pos, pw2, pb2, p_abn1);
    k_reduce_bn<<<1, 1024, 0, stream>>>(p_abn1, 2048, 64, 64, 1.f / E_, a1g, a1b, ss_a1);
    // 5) t1 + abn2 stats
    k_edge_t1<<<2048, 256, 0, stream>>>(pos, src, asrc16, buf_adst,
                                        pw1, pb1, ss_pos, pw2, pb2,
                                        ss_a1, aw1, ab1, buf_t1, p_abn2);
    k_reduce_bn<<<1, 1024, 0, stream>>>(p_abn2, 2048, 8, 8, 1.f / E_, a2g, a2b, ss_a2);
    // 6) softmax + weighted aggregate -> out (+ fused bn2 partials)
    k_node_aggr<<<4096, 256, 0, stream>>>(pos, src, buf_t1, ss_a2, aw2, ab2,
                                          hw16, ss_pos, pw1, pb1, pw2, pb2,
                                          buf_out, p_bn2);
    k_reduce_bn<<<1, 1024, 0, stream>>>(p_bn2, 4096, 64, 64, 1.f / N_, bn2g, bn2b, ss_bn2);
    // 7) y3 = relu(bn2(out)) @ W_out^T (+ fused bn3 partials)
    k_gemm_tile<<<1024, 256, 0, stream>>>(buf_out, W_out, nullptr, ss_bn2, buf_y, p_bn3);
    k_reduce_bn<<<1, 1024, 0, stream>>>(p_bn3, 1024, 64, 64, 1.f / N_, bn3g, bn3b, ss_bn3);
    // 8) out = relu(bn3(y3) + x)
    k_final<<<(N_ * C_ / 4) / 256, 256, 0, stream>>>(buf_y, ss_bn3, x, outp);

    (void)in_sizes; (void)n_in; (void)out_size; (void)ws_size;
}

// Round 10
// 373.036 us; speedup vs baseline: 1.0194x; 1.0194x over previous
//
#include <hip/hip_runtime.h>
#include <cstddef>

constexpr int N_ = 65536;
constexpr int K_ = 16;
constexpr int E_ = N_ * K_;      // 1048576
constexpr int C_ = 64;
#define EPS_ 1e-5f
#define SW 68   // LDS row stride (words) for GEMM tiles

typedef unsigned int uint_t;

// bf16 helpers (RNE pack, cheap unpack)
__device__ __forceinline__ uint_t bf16_rne(float f) {
    uint_t u = __float_as_uint(f);
    return (u + 0x7fffu + ((u >> 16) & 1u)) >> 16;
}
__device__ __forceinline__ float bf16_lo(uint_t p) { return __uint_as_float(p << 16); }
__device__ __forceinline__ float bf16_hi(uint_t p) { return __uint_as_float(p & 0xffff0000u); }

// ---------------------------------------------------------------------------
// BN stats reducer (R2: parallel, 4x unrolled, LDS tree).
__global__ __launch_bounds__(1024)
void k_reduce_bn(const float* __restrict__ part, int P, int nchp, int nch,
                 float invM, const float* __restrict__ g,
                 const float* __restrict__ b, float* __restrict__ ss)
{
    int t = threadIdx.x;
    int c = t & (nchp - 1);
    int r = t / nchp;
    int R = 1024 / nchp;
    int stride = 2 * nchp;
    float s0 = 0.f, s1 = 0.f, s2 = 0.f, s3 = 0.f;
    float q0 = 0.f, q1 = 0.f, q2 = 0.f, q3 = 0.f;
    int p = r;
    for (; p + 3 * R < P; p += 4 * R) {
        int i0 = p * stride + c;
        int i1 = (p + R) * stride + c;
        int i2 = (p + 2 * R) * stride + c;
        int i3 = (p + 3 * R) * stride + c;
        s0 += part[i0];        s1 += part[i1];
        s2 += part[i2];        s3 += part[i3];
        q0 += part[i0 + nchp]; q1 += part[i1 + nchp];
        q2 += part[i2 + nchp]; q3 += part[i3 + nchp];
    }
    for (; p < P; p += R) {
        s0 += part[p * stride + c];
        q0 += part[p * stride + nchp + c];
    }
    float s = (s0 + s1) + (s2 + s3);
    float q = (q0 + q1) + (q2 + q3);
    __shared__ float reds[1024], redq[1024];
    reds[t] = s; redq[t] = q;
    __syncthreads();
    for (int off = 512; off >= nchp; off >>= 1) {
        if (t < off) { reds[t] += reds[t + off]; redq[t] += redq[t + off]; }
        __syncthreads();
    }
    if (t < nch) {
        float mean = reds[t] * invM;
        float var  = fmaxf(redq[t] * invM - mean * mean, 0.f);
        float sc = g[t] * rsqrtf(var + EPS_);
        ss[t] = sc;
        ss[nchp + t] = b[t] - mean * sc;
    }
}

// ---------------------------------------------------------------------------
// R5 GEMM structure (LDS-tiled, coalesced).
__device__ __forceinline__ void stage_x(const float* __restrict__ in,
                                        const float* __restrict__ ss,
                                        float* __restrict__ Xs, int row0, int t)
{
#pragma unroll
    for (int it = 0; it < 4; ++it) {
        int m = t + 256 * it;
        int r = m >> 4, j = m & 15;
        float4 v = ((const float4*)in)[(size_t)(row0 + r) * 16 + j];
        if (ss) {
            float4 sc = ((const float4*)ss)[j];
            float4 sh = ((const float4*)(ss + 64))[j];
            v.x = fmaxf(fmaf(v.x, sc.x, sh.x), 0.f);
            v.y = fmaxf(fmaf(v.y, sc.y, sh.y), 0.f);
            v.z = fmaxf(fmaf(v.z, sc.z, sh.z), 0.f);
            v.w = fmaxf(fmaf(v.w, sc.w, sh.w), 0.f);
        }
        *(float4*)&Xs[r * SW + 4 * j] = v;
    }
}

__device__ __forceinline__ void stage_w(const float* __restrict__ W,
                                        float* __restrict__ Ws, int t)
{
#pragma unroll
    for (int it = 0; it < 4; ++it) {
        int m = t + 256 * it;
        int r = m >> 4, j = m & 15;
        *(float4*)&Ws[r * SW + 4 * j] = ((const float4*)W)[m];
    }
}

__device__ __forceinline__ void compute_tile(const float* __restrict__ Xs,
                                             const float* __restrict__ Ws,
                                             int tx, int ty, float acc[4][4])
{
#pragma unroll
    for (int r = 0; r < 4; ++r)
#pragma unroll
        for (int c = 0; c < 4; ++c) acc[r][c] = 0.f;
    for (int kc = 0; kc < 16; ++kc) {
        float4 xf[4], wf[4];
#pragma unroll
        for (int r = 0; r < 4; ++r)
            xf[r] = *(const float4*)&Xs[(tx + 16 * r) * SW + 4 * kc];
#pragma unroll
        for (int c = 0; c < 4; ++c)
            wf[c] = *(const float4*)&Ws[(ty + 16 * c) * SW + 4 * kc];
#pragma unroll
        for (int r = 0; r < 4; ++r)
#pragma unroll
            for (int c = 0; c < 4; ++c) {
                acc[r][c] = fmaf(xf[r].x, wf[c].x, acc[r][c]);
                acc[r][c] = fmaf(xf[r].y, wf[c].y, acc[r][c]);
                acc[r][c] = fmaf(xf[r].z, wf[c].z, acc[r][c]);
                acc[r][c] = fmaf(xf[r].w, wf[c].w, acc[r][c]);
            }
    }
}

__device__ __forceinline__ void write_tile(float* __restrict__ buf, int tx, int ty,
                                           const float acc[4][4],
                                           const float* __restrict__ bias,
                                           float* __restrict__ out, int row0, int t)
{
    __syncthreads();
#pragma unroll
    for (int r = 0; r < 4; ++r)
#pragma unroll
        for (int c = 0; c < 4; ++c)
            buf[(tx + 16 * r) * SW + ty + 16 * c] = acc[r][c];
    __syncthreads();
#pragma unroll
    for (int it = 0; it < 4; ++it) {
        int m = t + 256 * it;
        int r = m >> 4, j = m & 15;
        float4 v = *(const float4*)&buf[r * SW + 4 * j];
        if (bias) {
            float4 bv = ((const float4*)bias)[j];
            v.x += bv.x; v.y += bv.y; v.z += bv.z; v.w += bv.w;
        }
        ((float4*)out)[(size_t)(row0 + r) * 16 + j] = v;
    }
    __syncthreads();
}

// bf16 variant: rounds to bf16 (RNE) and stores 8B/lane coalesced.
__device__ __forceinline__ void write_tile_bf16(float* __restrict__ buf, int tx, int ty,
                                                const float acc[4][4],
                                                const float* __restrict__ bias,
                                                unsigned short* __restrict__ out,
                                                int row0, int t)
{
    __syncthreads();
#pragma unroll
    for (int r = 0; r < 4; ++r)
#pragma unroll
        for (int c = 0; c < 4; ++c)
            buf[(tx + 16 * r) * SW + ty + 16 * c] = acc[r][c];
    __syncthreads();
#pragma unroll
    for (int it = 0; it < 4; ++it) {
        int m = t + 256 * it;
        int r = m >> 4, j = m & 15;
        float4 v = *(const float4*)&buf[r * SW + 4 * j];
        if (bias) {
            float4 bv = ((const float4*)bias)[j];
            v.x += bv.x; v.y += bv.y; v.z += bv.z; v.w += bv.w;
        }
        uint2 o;
        o.x = bf16_rne(v.x) | (bf16_rne(v.y) << 16);
        o.y = bf16_rne(v.z) | (bf16_rne(v.w) << 16);
        ((uint2*)out)[(size_t)(row0 + r) * 16 + j] = o;
    }
    __syncthreads();
}

// y = (optional relu(bn(in))) @ W^T. Fused column-stats epilogue (R9 keep):
// store loop's j=t&15 is thread-invariant; Xs (dead) is the reduce scratch.
__global__ __launch_bounds__(256)
void k_gemm_tile(const float* __restrict__ in, const float* __restrict__ W,
                 const float* __restrict__ bias, const float* __restrict__ ss,
                 float* __restrict__ out, float* __restrict__ part)
{
    __shared__ float Xs[64 * SW];
    __shared__ float Ws[64 * SW];
    int t = threadIdx.x, tx = t & 15, ty = t >> 4;
    int row0 = blockIdx.x * 64;
    stage_x(in, ss, Xs, row0, t);
    stage_w(W, Ws, t);
    __syncthreads();
    float acc[4][4];
    compute_tile(Xs, Ws, tx, ty, acc);
    __syncthreads();
#pragma unroll
    for (int r = 0; r < 4; ++r)
#pragma unroll
        for (int c = 0; c < 4; ++c)
            Ws[(tx + 16 * r) * SW + ty + 16 * c] = acc[r][c];
    __syncthreads();
    float s0 = 0, s1 = 0, s2 = 0, s3 = 0, q0 = 0, q1 = 0, q2 = 0, q3 = 0;
#pragma unroll
    for (int it = 0; it < 4; ++it) {
        int m = t + 256 * it;
        int r = m >> 4, j = m & 15;
        float4 v = *(const float4*)&Ws[r * SW + 4 * j];
        if (bias) {
            float4 bv = ((const float4*)bias)[j];
            v.x += bv.x; v.y += bv.y; v.z += bv.z; v.w += bv.w;
        }
        ((float4*)out)[(size_t)(row0 + r) * 16 + j] = v;
        s0 += v.x; q0 = fmaf(v.x, v.x, q0);
        s1 += v.y; q1 = fmaf(v.y, v.y, q1);
        s2 += v.z; q2 = fmaf(v.z, v.z, q2);
        s3 += v.w; q3 = fmaf(v.w, v.w, q3);
    }
    float4* scr = (float4*)Xs;   // Xs dead after compute
    scr[t]       = make_float4(s0, s1, s2, s3);
    scr[256 + t] = make_float4(q0, q1, q2, q3);
    __syncthreads();
    if (t < 16) {   // thread t handles j=t (channels 4t..4t+3)
        float4 S = make_float4(0, 0, 0, 0), Q = make_float4(0, 0, 0, 0);
#pragma unroll
        for (int k = 0; k < 16; ++k) {
            float4 a = scr[k * 16 + t], b = scr[256 + k * 16 + t];
            S.x += a.x; S.y += a.y; S.z += a.z; S.w += a.w;
            Q.x += b.x; Q.y += b.y; Q.z += b.z; Q.w += b.w;
        }
        *(float4*)&part[blockIdx.x * 128 + 4 * t]      = S;
        *(float4*)&part[blockIdx.x * 128 + 64 + 4 * t] = Q;
    }
}

// h = relu(bn1(y)); asrc16 = bf16(h@Wa^T+ba); adst = h@Wb^T+bb (f32);
// hw16 = bf16(h@Wc^T+bc)
__global__ __launch_bounds__(256)
void k_gemm3_tile(const float* __restrict__ y, const float* __restrict__ ss,
                  const float* __restrict__ Wa, const float* __restrict__ ba,
                  const float* __restrict__ Wb, const float* __restrict__ bb,
                  const float* __restrict__ Wc, const float* __restrict__ bc,
                  unsigned short* __restrict__ oa16, float* __restrict__ ob,
                  unsigned short* __restrict__ oc16)
{
    __shared__ float Xs[64 * SW];
    __shared__ float Ws[64 * SW];
    int t = threadIdx.x, tx = t & 15, ty = t >> 4;
    int row0 = blockIdx.x * 64;
    stage_x(y, ss, Xs, row0, t);
    stage_w(Wa, Ws, t);
    __syncthreads();
    float acc[4][4];
    compute_tile(Xs, Ws, tx, ty, acc);
    write_tile_bf16(Ws, tx, ty, acc, ba, oa16, row0, t);
    stage_w(Wb, Ws, t);
    __syncthreads();
    compute_tile(Xs, Ws, tx, ty, acc);
    write_tile(Ws, tx, ty, acc, bb, ob, row0, t);
    stage_w(Wc, Ws, t);
    __syncthreads();
    compute_tile(Xs, Ws, tx, ty, acc);
    write_tile_bf16(Ws, tx, ty, acc, bc, oc16, row0, t);
}

// ---------------------------------------------------------------------------
// Stats of u = rel @ pos_w1^T + pos_b1 over E edges (3 channels, pad 4).
__global__ __launch_bounds__(256)
void k_pos_stats(const float* __restrict__ pos, const int* __restrict__ src,
                 const float* __restrict__ pw1, const float* __restrict__ pb1,
                 float* __restrict__ part)
{
    float s0 = 0, s1 = 0, s2 = 0, q0 = 0, q1 = 0, q2 = 0;
    int tid = blockIdx.x * 256 + threadIdx.x;
    for (int e = tid; e < E_; e += 1024 * 256) {
        int si = src[e], di = e >> 4;
        float rx = pos[3 * si + 0] - pos[3 * di + 0];
        float ry = pos[3 * si + 1] - pos[3 * di + 1];
        float rz = pos[3 * si + 2] - pos[3 * di + 2];
        float u0 = fmaf(rx, pw1[0], fmaf(ry, pw1[1], fmaf(rz, pw1[2], pb1[0])));
        float u1 = fmaf(rx, pw1[3], fmaf(ry, pw1[4], fmaf(rz, pw1[5], pb1[1])));
        float u2 = fmaf(rx, pw1[6], fmaf(ry, pw1[7], fmaf(rz, pw1[8], pb1[2])));
        s0 += u0; q0 = fmaf(u0, u0, q0);
        s1 += u1; q1 = fmaf(u1, u1, q1);
        s2 += u2; q2 = fmaf(u2, u2, q2);
    }
#pragma unroll
    for (int m = 1; m < 64; m <<= 1) {
        s0 += __shfl_xor(s0, m, 64); s1 += __shfl_xor(s1, m, 64); s2 += __shfl_xor(s2, m, 64);
        q0 += __shfl_xor(q0, m, 64); q1 += __shfl_xor(q1, m, 64); q2 += __shfl_xor(q2, m, 64);
    }
    __shared__ float red[4][8];
    int wv = threadIdx.x >> 6, ln = threadIdx.x & 63;
    if (ln == 0) {
        red[wv][0] = s0; red[wv][1] = s1; red[wv][2] = s2; red[wv][3] = 0.f;
        red[wv][4] = q0; red[wv][5] = q1; red[wv][6] = q2; red[wv][7] = 0.f;
    }
    __syncthreads();
    if (threadIdx.x < 8)
        part[blockIdx.x * 8 + threadIdx.x] =
            red[0][threadIdx.x] + red[1][threadIdx.x] + red[2][threadIdx.x] + red[3][threadIdx.x];
}

// ---------------------------------------------------------------------------
// R8 edge kernels (scalar math — R9 v2f reverted): group-per-node + per-lane
// d-precompute + bf16 tables. Lane l owns channels 4l..4l+3.

// Stats of a = bf16(a_src)[src]-a_dst[dst]+delta. Grid 2048 x 256.
__global__ __launch_bounds__(256)
void k_abn1_stats(const float* __restrict__ pos, const int* __restrict__ src,
                  const unsigned short* __restrict__ asrc16,
                  const float* __restrict__ adst,
                  const float* __restrict__ pw1, const float* __restrict__ pb1,
                  const float* __restrict__ sspos, const float* __restrict__ pw2,
                  const float* __restrict__ pb2, float* __restrict__ part)
{
    int t = threadIdx.x;
    int l = t & 15, g = t >> 4, wv = t >> 6;
    int c0 = 4 * l;
    float4 p0 = *(const float4*)(pw2 + 12 * l);
    float4 p1 = *(const float4*)(pw2 + 12 * l + 4);
    float4 p2 = *(const float4*)(pw2 + 12 * l + 8);
    float4 pb = *(const float4*)(pb2 + c0);
    float sa0 = 0, sa1 = 0, sa2 = 0, sa3 = 0;
    float qa0 = 0, qa1 = 0, qa2 = 0, qa3 = 0;
#pragma unroll
    for (int nn = 0; nn < 2; ++nn) {
        int n = blockIdx.x * 32 + nn * 16 + g;
        float4 dv = *(const float4*)(adst + (size_t)n * 64 + c0);
        float pnx = pos[3 * n + 0], pny = pos[3 * n + 1], pnz = pos[3 * n + 2];
        int si_l = src[n * 16 + l];
        float rx = pos[3 * si_l + 0] - pnx;
        float ry = pos[3 * si_l + 1] - pny;
        float rz = pos[3 * si_l + 2] - pnz;
        float u0 = fmaf(rx, pw1[0], fmaf(ry, pw1[1], fmaf(rz, pw1[2], pb1[0])));
        float u1 = fmaf(rx, pw1[3], fmaf(ry, pw1[4], fmaf(rz, pw1[5], pb1[1])));
        float u2 = fmaf(rx, pw1[6], fmaf(ry, pw1[7], fmaf(rz, pw1[8], pb1[2])));
        float dl0 = fmaxf(fmaf(u0, sspos[0], sspos[4]), 0.f);
        float dl1 = fmaxf(fmaf(u1, sspos[1], sspos[5]), 0.f);
        float dl2 = fmaxf(fmaf(u2, sspos[2], sspos[6]), 0.f);
        for (int k = 0; k < 16; ++k) {
            int si = __shfl(si_l, k, 16);
            float d0 = __shfl(dl0, k, 16);
            float d1 = __shfl(dl1, k, 16);
            float d2 = __shfl(dl2, k, 16);
            uint2 raw = ((const uint2*)asrc16)[(size_t)si * 16 + l];
            float avx = bf16_lo(raw.x), avy = bf16_hi(raw.x);
            float avz = bf16_lo(raw.y), avw = bf16_hi(raw.y);
            float del0 = fmaf(d0, p0.x, fmaf(d1, p0.y, fmaf(d2, p0.z, pb.x)));
            float del1 = fmaf(d0, p0.w, fmaf(d1, p1.x, fmaf(d2, p1.y, pb.y)));
            float del2 = fmaf(d0, p1.z, fmaf(d1, p1.w, fmaf(d2, p2.x, pb.z)));
            float del3 = fmaf(d0, p2.y, fmaf(d1, p2.z, fmaf(d2, p2.w, pb.w)));
            float a0 = avx - dv.x + del0;
            float a1 = avy - dv.y + del1;
            float a2 = avz - dv.z + del2;
            float a3 = avw - dv.w + del3;
            sa0 += a0; qa0 = fmaf(a0, a0, qa0);
            sa1 += a1; qa1 = fmaf(a1, a1, qa1);
            sa2 += a2; qa2 = fmaf(a2, a2, qa2);
            sa3 += a3; qa3 = fmaf(a3, a3, qa3);
        }
    }
#pragma unroll
    for (int m = 16; m <= 32; m <<= 1) {
        sa0 += __shfl_xor(sa0, m, 64); sa1 += __shfl_xor(sa1, m, 64);
        sa2 += __shfl_xor(sa2, m, 64); sa3 += __shfl_xor(sa3, m, 64);
        qa0 += __shfl_xor(qa0, m, 64); qa1 += __shfl_xor(qa1, m, 64);
        qa2 += __shfl_xor(qa2, m, 64); qa3 += __shfl_xor(qa3, m, 64);
    }
    __shared__ float red[4][128];
    if ((t & 63) < 16) {
        red[wv][c0 + 0] = sa0; red[wv][c0 + 1] = sa1;
        red[wv][c0 + 2] = sa2; red[wv][c0 + 3] = sa3;
        red[wv][64 + c0 + 0] = qa0; red[wv][64 + c0 + 1] = qa1;
        red[wv][64 + c0 + 2] = qa2; red[wv][64 + c0 + 3] = qa3;
    }
    __syncthreads();
    if (t < 128)
        part[blockIdx.x * 128 + t] = red[0][t] + red[1][t] + red[2][t] + red[3][t];
}

// ---------------------------------------------------------------------------
// t1 = relu(abn1(a)) @ attn_w1^T + attn_b1; abn2 stats. Grid 2048 x 256.
__global__ __launch_bounds__(256)
void k_edge_t1(const float* __restrict__ pos, const int* __restrict__ src,
               const unsigned short* __restrict__ asrc16,
               const float* __restrict__ adst,
               const float* __restrict__ pw1, const float* __restrict__ pb1,
               const float* __restrict__ sspos, const float* __restrict__ pw2,
               const float* __restrict__ pb2, const float* __restrict__ ssa1,
               const float* __restrict__ aw1, const float* __restrict__ ab1,
               float* __restrict__ t1, float* __restrict__ part)
{
    int t = threadIdx.x;
    int l = t & 15, g = t >> 4, wv = t >> 6;
    int c0 = 4 * l;
    int ch = 4 * (l & 1) + 2 * ((l >> 1) & 1) + ((l >> 2) & 1);
    float abv = ab1[ch];
    float4 p0 = *(const float4*)(pw2 + 12 * l);
    float4 p1 = *(const float4*)(pw2 + 12 * l + 4);
    float4 p2 = *(const float4*)(pw2 + 12 * l + 8);
    float4 pb = *(const float4*)(pb2 + c0);
    float4 sc = *(const float4*)(ssa1 + c0);
    float4 sh = *(const float4*)(ssa1 + 64 + c0);
    float4 w1[8];
#pragma unroll
    for (int jj = 0; jj < 8; ++jj) w1[jj] = *(const float4*)(aw1 + jj * 64 + c0);
    float sse = 0.f, ssq = 0.f;
#pragma unroll
    for (int nn = 0; nn < 2; ++nn) {
        int n = blockIdx.x * 32 + nn * 16 + g;
        float4 dv = *(const float4*)(adst + (size_t)n * 64 + c0);
        float pnx = pos[3 * n + 0], pny = pos[3 * n + 1], pnz = pos[3 * n + 2];
        int si_l = src[n * 16 + l];
        float rx = pos[3 * si_l + 0] - pnx;
        float ry = pos[3 * si_l + 1] - pny;
        float rz = pos[3 * si_l + 2] - pnz;
        float u0 = fmaf(rx, pw1[0], fmaf(ry, pw1[1], fmaf(rz, pw1[2], pb1[0])));
        float u1 = fmaf(rx, pw1[3], fmaf(ry, pw1[4], fmaf(rz, pw1[5], pb1[1])));
        float u2 = fmaf(rx, pw1[6], fmaf(ry, pw1[7], fmaf(rz, pw1[8], pb1[2])));
        float dl0 = fmaxf(fmaf(u0, sspos[0], sspos[4]), 0.f);
        float dl1 = fmaxf(fmaf(u1, sspos[1], sspos[5]), 0.f);
        float dl2 = fmaxf(fmaf(u2, sspos[2], sspos[6]), 0.f);
        for (int k = 0; k < 16; ++k) {
            int si = __shfl(si_l, k, 16);
            float d0 = __shfl(dl0, k, 16);
            float d1 = __shfl(dl1, k, 16);
            float d2 = __shfl(dl2, k, 16);
            uint2 raw = ((const uint2*)asrc16)[(size_t)si * 16 + l];
            float avx = bf16_lo(raw.x), avy = bf16_hi(raw.x);
            float avz = bf16_lo(raw.y), avw = bf16_hi(raw.y);
            float del0 = fmaf(d0, p0.x, fmaf(d1, p0.y, fmaf(d2, p0.z, pb.x)));
            float del1 = fmaf(d0, p0.w, fmaf(d1, p1.x, fmaf(d2, p1.y, pb.y)));
            float del2 = fmaf(d0, p1.z, fmaf(d1, p1.w, fmaf(d2, p2.x, pb.z)));
            float del3 = fmaf(d0, p2.y, fmaf(d1, p2.z, fmaf(d2, p2.w, pb.w)));
            float an0 = fmaxf(fmaf(avx - dv.x + del0, sc.x, sh.x), 0.f);
            float an1 = fmaxf(fmaf(avy - dv.y + del1, sc.y, sh.y), 0.f);
            float an2 = fmaxf(fmaf(avz - dv.z + del2, sc.z, sh.z), 0.f);
            float an3 = fmaxf(fmaf(avw - dv.w + del3, sc.w, sh.w), 0.f);
            float tp[8];
#pragma unroll
            for (int jj = 0; jj < 8; ++jj)
                tp[jj] = fmaf(an0, w1[jj].x, fmaf(an1, w1[jj].y,
                         fmaf(an2, w1[jj].z, an3 * w1[jj].w)));
            // reduce-scatter: 8 -> 4 -> 2 -> 1 values
            float s4[4];
#pragma unroll
            for (int j = 0; j < 4; ++j) {
                float send = (l & 1) ? tp[j] : tp[j + 4];
                float recv = __shfl_xor(send, 1, 64);
                s4[j] = ((l & 1) ? tp[j + 4] : tp[j]) + recv;
            }
            float s2[2];
#pragma unroll
            for (int j = 0; j < 2; ++j) {
                float send = (l & 2) ? s4[j] : s4[j + 2];
                float recv = __shfl_xor(send, 2, 64);
                s2[j] = ((l & 2) ? s4[j + 2] : s4[j]) + recv;
            }
            float send = (l & 4) ? s2[0] : s2[1];
            float recv = __shfl_xor(send, 4, 64);
            float s1 = ((l & 4) ? s2[1] : s2[0]) + recv;
            s1 += __shfl_xor(s1, 8, 64);
            float o = s1 + abv;
            if (l < 8) t1[(size_t)(n * 16 + k) * 8 + ch] = o;
            sse += o; ssq = fmaf(o, o, ssq);
        }
    }
#pragma unroll
    for (int m = 16; m <= 32; m <<= 1) {
        sse += __shfl_xor(sse, m, 64);
        ssq += __shfl_xor(ssq, m, 64);
    }
    __shared__ float red[4][16];
    if ((t & 63) < 8) { red[wv][ch] = sse; red[wv][8 + ch] = ssq; }
    __syncthreads();
    if (t < 16)
        part[blockIdx.x * 16 + t] = red[0][t] + red[1][t] + red[2][t] + red[3][t];
}

// ---------------------------------------------------------------------------
// Softmax + weighted aggregate, group-per-node; fused bn2-stats epilogue
// (R9 keep, scalar math). Grid 4096 x 256 (16 nodes/blk).
__global__ __launch_bounds__(256)
void k_node_aggr(const float* __restrict__ pos, const int* __restrict__ src,
                 const float* __restrict__ t1, const float* __restrict__ ssa2,
                 const float* __restrict__ aw2, const float* __restrict__ ab2,
                 const unsigned short* __restrict__ hw16,
                 const float* __restrict__ sspos,
                 const float* __restrict__ pw1, const float* __restrict__ pb1,
                 const float* __restrict__ pw2, const float* __restrict__ pb2,
                 float* __restrict__ out, float* __restrict__ part)
{
    __shared__ float alds[16][196];   // [group][k*12 + ch8]; later stats scratch
    int t = threadIdx.x, l = t & 15, g = t >> 4;
    int c0 = 4 * l;
    float4 p0 = *(const float4*)(pw2 + 12 * l);
    float4 p1 = *(const float4*)(pw2 + 12 * l + 4);
    float4 p2 = *(const float4*)(pw2 + 12 * l + 8);
    float4 pb = *(const float4*)(pb2 + c0);
    int alof = (l & 1) * 4;
    int n = blockIdx.x * 16 + g;
    int e = n * 16 + l;
    // ---- phase A: per-edge attention logits + softmax over the group
    const float4* t4 = (const float4*)(t1 + (size_t)e * 8);
    float4 ta = t4[0], tb = t4[1];
    float tv[8] = {ta.x, ta.y, ta.z, ta.w, tb.x, tb.y, tb.z, tb.w};
    float tn[8];
#pragma unroll
    for (int j = 0; j < 8; ++j)
        tn[j] = fmaxf(fmaf(tv[j], ssa2[j], ssa2[8 + j]), 0.f);
    float al[8];
#pragma unroll
    for (int j = 0; j < 8; ++j) {
        float acc = ab2[j];
#pragma unroll
        for (int i = 0; i < 8; ++i) acc = fmaf(tn[i], aw2[j * 8 + i], acc);
        float m = acc;
#pragma unroll
        for (int msk = 1; msk < 16; msk <<= 1) m = fmaxf(m, __shfl_xor(m, msk, 64));
        float ex = __expf(acc - m);
        float sm = ex;
#pragma unroll
        for (int msk = 1; msk < 16; msk <<= 1) sm += __shfl_xor(sm, msk, 64);
        al[j] = ex / sm;
    }
    *(float4*)&alds[g][l * 12]     = make_float4(al[0], al[1], al[2], al[3]);
    *(float4*)&alds[g][l * 12 + 4] = make_float4(al[4], al[5], al[6], al[7]);
    int silane = src[e];
    float pnx = pos[3 * n + 0], pny = pos[3 * n + 1], pnz = pos[3 * n + 2];
    // own-edge d
    float rx = pos[3 * silane + 0] - pnx;
    float ry = pos[3 * silane + 1] - pny;
    float rz = pos[3 * silane + 2] - pnz;
    float u0 = fmaf(rx, pw1[0], fmaf(ry, pw1[1], fmaf(rz, pw1[2], pb1[0])));
    float u1 = fmaf(rx, pw1[3], fmaf(ry, pw1[4], fmaf(rz, pw1[5], pb1[1])));
    float u2 = fmaf(rx, pw1[6], fmaf(ry, pw1[7], fmaf(rz, pw1[8], pb1[2])));
    float dl0 = fmaxf(fmaf(u0, sspos[0], sspos[4]), 0.f);
    float dl1 = fmaxf(fmaf(u1, sspos[1], sspos[5]), 0.f);
    float dl2 = fmaxf(fmaf(u2, sspos[2], sspos[6]), 0.f);
    // ---- phase B: accumulate own 4 channels over the node's 16 edges
    float a0 = 0.f, a1 = 0.f, a2 = 0.f, a3 = 0.f;
#pragma unroll 4
    for (int k = 0; k < 16; ++k) {
        int sk = __shfl(silane, k, 16);
        float d0 = __shfl(dl0, k, 16);
        float d1 = __shfl(dl1, k, 16);
        float d2 = __shfl(dl2, k, 16);
        uint2 raw = ((const uint2*)hw16)[(size_t)sk * 16 + l];
        float hvx = bf16_lo(raw.x), hvy = bf16_hi(raw.x);
        float hvz = bf16_lo(raw.y), hvw = bf16_hi(raw.y);
        float4 alv = *(const float4*)&alds[g][k * 12 + alof];
        float del0 = fmaf(d0, p0.x, fmaf(d1, p0.y, fmaf(d2, p0.z, pb.x)));
        float del1 = fmaf(d0, p0.w, fmaf(d1, p1.x, fmaf(d2, p1.y, pb.y)));
        float del2 = fmaf(d0, p1.z, fmaf(d1, p1.w, fmaf(d2, p2.x, pb.z)));
        float del3 = fmaf(d0, p2.y, fmaf(d1, p2.z, fmaf(d2, p2.w, pb.w)));
        a0 = fmaf(alv.x, hvx + del0, a0);
        a1 = fmaf(alv.y, hvy + del1, a1);
        a2 = fmaf(alv.z, hvz + del2, a2);
        a3 = fmaf(alv.w, hvw + del3, a3);
    }
    *(float4*)(out + (size_t)n * 64 + c0) = make_float4(a0, a1, a2, a3);
    // ---- fused bn2 stats: reduce over the block's 16 nodes per channel
    __syncthreads();   // all alds reads done
    float4* scr = (float4*)&alds[0][0];   // 512 float4 <= 3136 floats OK
    scr[g * 16 + l]       = make_float4(a0, a1, a2, a3);
    scr[256 + g * 16 + l] = make_float4(a0 * a0, a1 * a1, a2 * a2, a3 * a3);
    __syncthreads();
    if (t < 16) {   // thread t handles l=t (channels 4t..4t+3)
        float4 S = make_float4(0, 0, 0, 0), Q = make_float4(0, 0, 0, 0);
#pragma unroll
        for (int k = 0; k < 16; ++k) {
            float4 a = scr[k * 16 + t], b = scr[256 + k * 16 + t];
            S.x += a.x; S.y += a.y; S.z += a.z; S.w += a.w;
            Q.x += b.x; Q.y += b.y; Q.z += b.z; Q.w += b.w;
        }
        *(float4*)&part[blockIdx.x * 128 + 4 * t]      = S;
        *(float4*)&part[blockIdx.x * 128 + 64 + 4 * t] = Q;
    }
}

// ---------------------------------------------------------------------------
// out = relu(bn3(y3) + x_skip)
__global__ __launch_bounds__(256)
void k_final(const float* __restrict__ y3, const float* __restrict__ ss3,
             const float* __restrict__ x, float* __restrict__ out)
{
    int i = blockIdx.x * 256 + threadIdx.x;   // float4 index
    int c4 = i & 15;
    float4 sc = ((const float4*)ss3)[c4];
    float4 sh = ((const float4*)(ss3 + 64))[c4];
    float4 v  = ((const float4*)y3)[i];
    float4 xs = ((const float4*)x)[i];
    float4 o;
    o.x = fmaxf(fmaf(v.x, sc.x, sh.x) + xs.x, 0.f);
    o.y = fmaxf(fmaf(v.y, sc.y, sh.y) + xs.y, 0.f);
    o.z = fmaxf(fmaf(v.z, sc.z, sh.z) + xs.z, 0.f);
    o.w = fmaxf(fmaf(v.w, sc.w, sh.w) + xs.w, 0.f);
    ((float4*)out)[i] = o;
}

// ---------------------------------------------------------------------------
extern "C" void kernel_launch(void* const* d_in, const int* in_sizes, int n_in,
                              void* d_out, int out_size, void* d_ws, size_t ws_size,
                              hipStream_t stream)
{
    const float* x    = (const float*)d_in[0];
    const float* pos  = (const float*)d_in[1];
    const int*   src  = (const int*)d_in[2];           // edge_index row 0
    const float* W_in = (const float*)d_in[3];
    const float* W_out= (const float*)d_in[4];
    const float* pw1  = (const float*)d_in[5];
    const float* pb1  = (const float*)d_in[6];
    const float* pbg  = (const float*)d_in[7];
    const float* pbb  = (const float*)d_in[8];
    const float* pw2  = (const float*)d_in[9];
    const float* pb2  = (const float*)d_in[10];
    const float* a1g  = (const float*)d_in[11];
    const float* a1b  = (const float*)d_in[12];
    const float* aw1  = (const float*)d_in[13];
    const float* ab1  = (const float*)d_in[14];
    const float* a2g  = (const float*)d_in[15];
    const float* a2b  = (const float*)d_in[16];
    const float* aw2  = (const float*)d_in[17];
    const float* ab2  = (const float*)d_in[18];
    const float* linw = (const float*)d_in[19];
    const float* linb = (const float*)d_in[20];
    const float* srcw = (const float*)d_in[21];
    const float* srcb = (const float*)d_in[22];
    const float* dstw = (const float*)d_in[23];
    const float* dstb = (const float*)d_in[24];
    const float* bn1g = (const float*)d_in[25];
    const float* bn1b = (const float*)d_in[26];
    const float* bn2g = (const float*)d_in[27];
    const float* bn2b = (const float*)d_in[28];
    const float* bn3g = (const float*)d_in[29];
    const float* bn3b = (const float*)d_in[30];
    float* outp = (float*)d_out;

    float* ws = (float*)d_ws;
    const size_t NC = (size_t)N_ * C_;
    float* buf_y     = ws;                       // y1, later y3
    float* buf_adst  = ws + NC;                  // a_dst f32; later reused as out
    unsigned short* asrc16 = (unsigned short*)(ws + 2 * NC);       // NC/2 floats
    unsigned short* hw16   = (unsigned short*)(ws + 2 * NC + NC / 2);
    float* buf_t1    = ws + 3 * NC;              // [E,8] f32
    float* pbase     = ws + 3 * NC + (size_t)E_ * 8;
    float* p_bn1  = pbase;                 // 1024*128
    float* p_pos  = p_bn1  + 1024 * 128;   // 1024*8
    float* p_abn2 = p_pos  + 1024 * 8;     // 2048*16
    float* p_bn2  = p_abn2 + 2048 * 16;    // 4096*128
    float* p_bn3  = p_bn2  + 4096 * 128;   // 1024*128
    float* ssb    = p_bn3  + 1024 * 128;
    float* ss_bn1 = ssb;         // [scale 64][shift 64]
    float* ss_pos = ssb + 128;   // [scale 4][shift 4]
    float* ss_a1  = ssb + 136;   // 128
    float* ss_a2  = ssb + 264;   // 16
    float* ss_bn2 = ssb + 280;   // 128
    float* ss_bn3 = ssb + 408;   // 128
    // p_abn1 (2048*128 = 1 MB) aliases buf_t1: consumed by its reducer BEFORE
    // k_edge_t1 writes t1 into the same region.
    float* p_abn1 = buf_t1;
    // buf_out aliases buf_adst: adst last read by k_edge_t1.
    float* buf_out = buf_adst;

    // 1) y1 = x @ W_in^T (+ fused bn1 partials)
    k_gemm_tile<<<1024, 256, 0, stream>>>(x, W_in, nullptr, nullptr, buf_y, p_bn1);
    k_reduce_bn<<<1, 1024, 0, stream>>>(p_bn1, 1024, 64, 64, 1.f / N_, bn1g, bn1b, ss_bn1);
    // 2) h = relu(bn1(y1)); asrc16 (bf16) / adst (f32) / hw16 (bf16)
    k_gemm3_tile<<<1024, 256, 0, stream>>>(buf_y, ss_bn1, srcw, srcb, dstw, dstb, linw, linb,
                                           asrc16, buf_adst, hw16);
    // 3) pos-BN stats
    k_pos_stats<<<1024, 256, 0, stream>>>(pos, src, pw1, pb1, p_pos);
    k_reduce_bn<<<1, 1024, 0, stream>>>(p_pos, 1024, 4, 3, 1.f / E_, pbg, pbb, ss_pos);
    // 4) attn_bn1 stats
    k_abn1_stats<<<2048, 256, 0, stream>>>(pos, src, asrc16, buf_adst,
                                           pw1, pb1, ss_pos, pw2, pb2, p_abn1);
    k_reduce_bn<<<1, 1024, 0, stream>>>(p_abn1, 2048, 64, 64, 1.f / E_, a1g, a1b, ss_a1);
    // 5) t1 + abn2 stats
    k_edge_t1<<<2048, 256, 0, stream>>>(pos, src, asrc16, buf_adst,
                                        pw1, pb1, ss_pos, pw2, pb2,
                                        ss_a1, aw1, ab1, buf_t1, p_abn2);
    k_reduce_bn<<<1, 1024, 0, stream>>>(p_abn2, 2048, 8, 8, 1.f / E_, a2g, a2b, ss_a2);
    // 6) softmax + weighted aggregate -> out (+ fused bn2 partials)
    k_node_aggr<<<4096, 256, 0, stream>>>(pos, src, buf_t1, ss_a2, aw2, ab2,
                                          hw16, ss_pos, pw1, pb1, pw2, pb2,
                                          buf_out, p_bn2);
    k_reduce_bn<<<1, 1024, 0, stream>>>(p_bn2, 4096, 64, 64, 1.f / N_, bn2g, bn2b, ss_bn2);
    // 7) y3 = relu(bn2(out)) @ W_out^T (+ fused bn3 partials)
    k_gemm_tile<<<1024, 256, 0, stream>>>(buf_out, W_out, nullptr, ss_bn2, buf_y, p_bn3);
    k_reduce_bn<<<1, 1024, 0, stream>>>(p_bn3, 1024, 64, 64, 1.f / N_, bn3g, bn3b, ss_bn3);
    // 8) out = relu(bn3(y3) + x)
    k_final<<<(N_ * C_ / 4) / 256, 256, 0, stream>>>(buf_y, ss_bn3, x, outp);

    (void)in_sizes; (void)n_in; (void)out_size; (void)ws_size;
}